// Round 3
// baseline (337.227 us; speedup 1.0000x reference)
//
#include <hip/hip_runtime.h>
#include <math.h>

#define HW 16384

typedef unsigned int uint;
typedef short bfrag __attribute__((ext_vector_type(8)));   // 8 bf16 (4 VGPRs)
typedef float f32x4 __attribute__((ext_vector_type(4)));   // 4 fp32 acc

union FragCvt { uint4 u; bfrag v; };

// round-to-nearest-even f32 -> bf16, pack two into a dword
__device__ inline uint pack2bf(float a, float b) {
  uint ua = __builtin_bit_cast(uint, a);
  uint ub = __builtin_bit_cast(uint, b);
  ua = (ua + 0x7FFFu + ((ua >> 16) & 1u)) >> 16;
  ub = (ub + 0x7FFFu + ((ub >> 16) & 1u)) & 0xFFFF0000u;
  return ua | ub;
}

// split 8 f32 into hi-bf16 frag and lo-bf16 frag (hi = RNE(x), lo = RNE(x-hi))
__device__ inline void cvt_hilo(float4 a, float4 b, bfrag& hi, bfrag& lo) {
  float v0[8] = {a.x, a.y, a.z, a.w, b.x, b.y, b.z, b.w};
  uint hv[4], lv[4];
  #pragma unroll
  for (int i = 0; i < 4; ++i) {
    float x0 = v0[2 * i], x1 = v0[2 * i + 1];
    uint h = pack2bf(x0, x1);
    float h0 = __builtin_bit_cast(float, h << 16);
    float h1 = __builtin_bit_cast(float, h & 0xFFFF0000u);
    hv[i] = h;
    lv[i] = pack2bf(x0 - h0, x1 - h1);
  }
  FragCvt ch, cl;
  ch.u = make_uint4(hv[0], hv[1], hv[2], hv[3]);
  cl.u = make_uint4(lv[0], lv[1], lv[2], lv[3]);
  hi = ch.v;
  lo = cl.v;
}

// ---------------------------------------------------------------------------
// mod[b,c] = 1 + (k_v[:, :192] @ w_kR.T) for c<192, else 1 + (k_v[:,192:] @ w_kI.T)
__global__ __launch_bounds__(256) void mod_kernel(
    const float* __restrict__ kv, const float* __restrict__ wkR,
    const float* __restrict__ wkI, float* __restrict__ mod)
{
  int b = blockIdx.x;
  int c = threadIdx.x;
  const float* kvb = kv + b * 256;
  float s = 0.f;
  if (c < 192) {
    const float* wr = wkR + c * 192;
    for (int j = 0; j < 192; ++j) s += kvb[j] * wr[j];
  } else {
    const float* wi = wkI + (c - 192) * 64;
    for (int j = 0; j < 64; ++j) s += kvb[192 + j] * wi[j];
  }
  mod[b * 256 + c] = 1.f + s;
}

// ---------------------------------------------------------------------------
// bf16-MFMA GEMM: Y[b][M,HW] = W[M,K] @ (X[b][c0+k,:] * mod[b,c0+k])
// 128x128 tile, BK=32, 256 threads = 4 waves (2x2 of 64x64), 4x4 frags of
// 16x16x32. f32 inputs converted RNE->bf16 during LDS staging; f32 accum.
// LDS layout [row][k] with k-stride 40 bf16 (80 B): 16B-aligned b128 frags,
// 2 lanes/bank (free). A = W rows, B stored as [pixel][k].
// MFMA operands are called as mfma(pixel_frag, w_frag): C rows = pixels, so
// each lane's 4 acc regs are 4 consecutive pixels -> direct float4 C-stores
// (16 dwordx4/thread instead of 64 scalar dwords).
__global__ __launch_bounds__(256) void mgemm(
    const float* __restrict__ W, int ldW, size_t Wbstride,
    const float* __restrict__ X, int c0, size_t Xbstride,
    const float* __restrict__ mod,
    float* __restrict__ Y, size_t Ybstride, int K)
{
  int b = blockIdx.z, mt = blockIdx.y, nt = blockIdx.x;
  const float* Wb = W + (size_t)b * Wbstride + (size_t)mt * 128 * ldW;
  const float* Xb = X + (size_t)b * Xbstride + (size_t)c0 * HW + nt * 128;
  float* Yb = Y + (size_t)b * Ybstride + (size_t)mt * 128 * HW + nt * 128;

  __shared__ unsigned short Al[128 * 40];
  __shared__ unsigned short Bl[128 * 40];

  int t = threadIdx.x;
  int w = t >> 6, l = t & 63;
  int wm = (w >> 1) * 64, wn = (w & 1) * 64;   // wm: outch base, wn: pixel base
  int lm = l & 15, lk = (l >> 4) * 8;

  int am = t >> 1, ako = (t & 1) * 16;     // A staging: row, k-offset (16 f32)
  int bn = t & 127, bo = (t >> 7) * 8;     // B staging: pixel, k-octet base

  f32x4 acc[4][4];
  #pragma unroll
  for (int fi = 0; fi < 4; ++fi)
    #pragma unroll
    for (int fj = 0; fj < 4; ++fj) acc[fi][fj] = {0.f, 0.f, 0.f, 0.f};

  for (int k0 = 0; k0 < K; k0 += 32) {
    // ---- global loads into registers
    const float* wsrc = Wb + (size_t)am * ldW + k0 + ako;
    float4 a0 = *(const float4*)(wsrc);
    float4 a1 = *(const float4*)(wsrc + 4);
    float4 a2 = *(const float4*)(wsrc + 8);
    float4 a3 = *(const float4*)(wsrc + 12);

    float xr[2][8];
    #pragma unroll
    for (int i = 0; i < 2; ++i) {
      int kb = k0 + bo + i * 16;
      #pragma unroll
      for (int r = 0; r < 8; ++r)
        xr[i][r] = Xb[(size_t)(kb + r) * HW + bn];
    }
    float sc[2][8];
    if (mod) {
      const float* mp = mod + b * 256 + c0 + k0 + bo;
      #pragma unroll
      for (int i = 0; i < 2; ++i) {
        float4 m0 = *(const float4*)(mp + i * 16);
        float4 m1 = *(const float4*)(mp + i * 16 + 4);
        sc[i][0] = m0.x; sc[i][1] = m0.y; sc[i][2] = m0.z; sc[i][3] = m0.w;
        sc[i][4] = m1.x; sc[i][5] = m1.y; sc[i][6] = m1.z; sc[i][7] = m1.w;
      }
    } else {
      #pragma unroll
      for (int i = 0; i < 2; ++i)
        #pragma unroll
        for (int r = 0; r < 8; ++r) sc[i][r] = 1.f;
    }

    __syncthreads();   // previous iteration's LDS reads done

    // ---- stage A (convert to bf16)
    uint4 aw0, aw1;
    aw0.x = pack2bf(a0.x, a0.y); aw0.y = pack2bf(a0.z, a0.w);
    aw0.z = pack2bf(a1.x, a1.y); aw0.w = pack2bf(a1.z, a1.w);
    aw1.x = pack2bf(a2.x, a2.y); aw1.y = pack2bf(a2.z, a2.w);
    aw1.z = pack2bf(a3.x, a3.y); aw1.w = pack2bf(a3.z, a3.w);
    *(uint4*)&Al[am * 40 + ako] = aw0;
    *(uint4*)&Al[am * 40 + ako + 8] = aw1;

    // ---- stage B (mod-scale + convert)
    #pragma unroll
    for (int i = 0; i < 2; ++i) {
      uint4 bw;
      bw.x = pack2bf(xr[i][0] * sc[i][0], xr[i][1] * sc[i][1]);
      bw.y = pack2bf(xr[i][2] * sc[i][2], xr[i][3] * sc[i][3]);
      bw.z = pack2bf(xr[i][4] * sc[i][4], xr[i][5] * sc[i][5]);
      bw.w = pack2bf(xr[i][6] * sc[i][6], xr[i][7] * sc[i][7]);
      *(uint4*)&Bl[bn * 40 + bo + i * 16] = bw;
    }

    __syncthreads();

    // ---- fragments + MFMA (pixel frag as A-operand -> C rows are pixels)
    bfrag af[4], bfr[4];
    #pragma unroll
    for (int fj = 0; fj < 4; ++fj) {
      FragCvt cv;
      cv.u = *(const uint4*)&Al[(wm + fj * 16 + lm) * 40 + lk];
      af[fj] = cv.v;
    }
    #pragma unroll
    for (int fi = 0; fi < 4; ++fi) {
      FragCvt cv;
      cv.u = *(const uint4*)&Bl[(wn + fi * 16 + lm) * 40 + lk];
      bfr[fi] = cv.v;
    }
    #pragma unroll
    for (int fi = 0; fi < 4; ++fi)
      #pragma unroll
      for (int fj = 0; fj < 4; ++fj)
        acc[fi][fj] = __builtin_amdgcn_mfma_f32_16x16x32_bf16(
            bfr[fi], af[fj], acc[fi][fj], 0, 0, 0);
  }

  // ---- store C: rows = pixels. col(lane&15) = outch, row = (l>>4)*4 + reg
  // -> acc[fi][fj] is float4 of 4 consecutive pixels for one outch row.
  int ph = (l >> 4) * 4;
  #pragma unroll
  for (int fi = 0; fi < 4; ++fi)
    #pragma unroll
    for (int fj = 0; fj < 4; ++fj)
      *(f32x4*)&Yb[(size_t)(wm + fj * 16 + lm) * HW + wn + fi * 16 + ph] =
          acc[fi][fj];
}

// ---------------------------------------------------------------------------
// depthwise 3x3, SAME zero pad. One block per (channel, batch).
__global__ __launch_bounds__(256) void dwconv_kernel(
    const float* __restrict__ in, size_t in_bstride,
    const float* __restrict__ wdw,
    float* __restrict__ out, size_t out_bstride,
    float* __restrict__ ssq)
{
  int c = blockIdx.x;
  int b = blockIdx.y;
  int t = threadIdx.x;
  int r = t >> 5;
  int xq = t & 31;

  const float4* ip4 = (const float4*)(in + (size_t)b * in_bstride + ((size_t)c << 14));
  float4* op4 = (float4*)(out + (size_t)b * out_bstride + ((size_t)c << 14));
  const float* wp = wdw + c * 9;
  float w0 = wp[0], w1 = wp[1], w2 = wp[2], w3 = wp[3], w4 = wp[4],
        w5 = wp[5], w6 = wp[6], w7 = wp[7], w8 = wp[8];

  const float4 z4 = make_float4(0.f, 0.f, 0.f, 0.f);
  int y0 = r << 4;

  float4 a = (y0 > 0) ? ip4[((y0 - 1) << 5) + xq] : z4;
  float4 bb = ip4[(y0 << 5) + xq];

  float aL = __shfl_up(a.w, 1);  if (xq == 0)  aL = 0.f;
  float aR = __shfl_down(a.x, 1); if (xq == 31) aR = 0.f;
  float bL = __shfl_up(bb.w, 1); if (xq == 0)  bL = 0.f;
  float bR = __shfl_down(bb.x, 1); if (xq == 31) bR = 0.f;

  float ss = 0.f;
  #pragma unroll
  for (int i = 0; i < 16; ++i) {
    int y = y0 + i;
    int yc = (y + 1 < 128) ? (y + 1) : 127;
    float4 cc = ip4[(yc << 5) + xq];
    if (y + 1 >= 128) { cc.x = 0.f; cc.y = 0.f; cc.z = 0.f; cc.w = 0.f; }
    float cL = __shfl_up(cc.w, 1);  if (xq == 0)  cL = 0.f;
    float cR = __shfl_down(cc.x, 1); if (xq == 31) cR = 0.f;

    float4 o;
    o.x = w0 * aL  + w1 * a.x + w2 * a.y +
          w3 * bL  + w4 * bb.x + w5 * bb.y +
          w6 * cL  + w7 * cc.x + w8 * cc.y;
    o.y = w0 * a.x + w1 * a.y + w2 * a.z +
          w3 * bb.x + w4 * bb.y + w5 * bb.z +
          w6 * cc.x + w7 * cc.y + w8 * cc.z;
    o.z = w0 * a.y + w1 * a.z + w2 * a.w +
          w3 * bb.y + w4 * bb.z + w5 * bb.w +
          w6 * cc.y + w7 * cc.z + w8 * cc.w;
    o.w = w0 * a.z + w1 * a.w + w2 * aR +
          w3 * bb.z + w4 * bb.w + w5 * bR +
          w6 * cc.z + w7 * cc.w + w8 * cR;

    op4[(y << 5) + xq] = o;
    ss += o.x * o.x + o.y * o.y + o.z * o.z + o.w * o.w;

    a = bb; aL = bL; aR = bR;
    bb = cc; bL = cL; bR = cR;
  }

  if (ssq) {
    #pragma unroll
    for (int off = 32; off > 0; off >>= 1) ss += __shfl_down(ss, off);
    __shared__ float red[4];
    if ((t & 63) == 0) red[t >> 6] = ss;
    __syncthreads();
    if (t == 0) ssq[b * 256 + c] = red[0] + red[1] + red[2] + red[3];
  }
}

// ---------------------------------------------------------------------------
// S[b,h,c,d] += sum_p qdw[b,h*32+c,p] * kdw[b,h*32+d,p]  (unnormalized Gram)
// MFMA split-K: both operands are [channel][pixel] = [m][k]/[n][k], which is
// exactly the 16x16x32 A/B fragment layout -> direct 16B global loads, no LDS
// staging, no barriers in the main loop. hi/lo bf16 decomposition keeps
// ~16-bit mantissa precision (S ~= Ahi*Bhi + Ahi*Blo + Alo*Bhi).
// Wave w of each block handles pixels [chunk*1024 + w*256, +256).
__global__ __launch_bounds__(256) void gram_kernel(
    const float* __restrict__ qdw, const float* __restrict__ kdw,
    float* __restrict__ S)
{
  int chunk = blockIdx.x, h = blockIdx.y, b = blockIdx.z;
  int t = threadIdx.x;
  int w = t >> 6, l = t & 63;
  int lm = l & 15;
  int lk8 = (l >> 4) * 8;

  const float* qh = qdw + (((size_t)b * 256 + h * 32) << 14);
  const float* kh = kdw + (((size_t)b * 256 + h * 32) << 14);
  const float* q0 = qh + ((size_t)lm << 14);
  const float* q1 = q0 + ((size_t)16 << 14);
  const float* k0 = kh + ((size_t)lm << 14);
  const float* k1 = k0 + ((size_t)16 << 14);

  int px0 = chunk * 1024 + w * 256 + lk8;

  f32x4 acc[2][2], accl[2][2];
  #pragma unroll
  for (int mi = 0; mi < 2; ++mi)
    #pragma unroll
    for (int nj = 0; nj < 2; ++nj) {
      acc[mi][nj] = {0.f, 0.f, 0.f, 0.f};
      accl[mi][nj] = {0.f, 0.f, 0.f, 0.f};
    }

  #pragma unroll 2
  for (int s = 0; s < 8; ++s) {
    int px = px0 + s * 32;
    float4 a0 = *(const float4*)(q0 + px);
    float4 a1 = *(const float4*)(q0 + px + 4);
    float4 a2 = *(const float4*)(q1 + px);
    float4 a3 = *(const float4*)(q1 + px + 4);
    float4 b0 = *(const float4*)(k0 + px);
    float4 b1 = *(const float4*)(k0 + px + 4);
    float4 b2 = *(const float4*)(k1 + px);
    float4 b3 = *(const float4*)(k1 + px + 4);

    bfrag qhF[2], qlF[2], khF[2], klF[2];
    cvt_hilo(a0, a1, qhF[0], qlF[0]);
    cvt_hilo(a2, a3, qhF[1], qlF[1]);
    cvt_hilo(b0, b1, khF[0], klF[0]);
    cvt_hilo(b2, b3, khF[1], klF[1]);

    #pragma unroll
    for (int mi = 0; mi < 2; ++mi)
      #pragma unroll
      for (int nj = 0; nj < 2; ++nj) {
        acc[mi][nj] = __builtin_amdgcn_mfma_f32_16x16x32_bf16(
            qhF[mi], khF[nj], acc[mi][nj], 0, 0, 0);
        accl[mi][nj] = __builtin_amdgcn_mfma_f32_16x16x32_bf16(
            qhF[mi], klF[nj], accl[mi][nj], 0, 0, 0);
        accl[mi][nj] = __builtin_amdgcn_mfma_f32_16x16x32_bf16(
            qlF[mi], khF[nj], accl[mi][nj], 0, 0, 0);
      }
  }

  // reduce the 4 waves' partial 32x32 tiles through LDS, then one
  // atomicAdd per element per block (16 adds/address across the grid).
  __shared__ float red[4][1024];
  int orow = (l >> 4) * 4;
  #pragma unroll
  for (int mi = 0; mi < 2; ++mi)
    #pragma unroll
    for (int nj = 0; nj < 2; ++nj)
      #pragma unroll
      for (int r = 0; r < 4; ++r)
        red[w][(mi * 16 + orow + r) * 32 + nj * 16 + lm] =
            acc[mi][nj][r] + accl[mi][nj][r];
  __syncthreads();
  float* Sp = S + (((size_t)b * 8 + h) << 10);
  for (int idx = t; idx < 1024; idx += 256)
    atomicAdd(&Sp[idx], red[0][idx] + red[1][idx] + red[2][idx] + red[3][idx]);
}

// ---------------------------------------------------------------------------
// in-place: S <- softmax_d( S / (max(|q|,eps)*max(|k|,eps)) * temp[h] )
__global__ __launch_bounds__(64) void softmax_kernel(
    float* __restrict__ S, const float* __restrict__ ssq,
    const float* __restrict__ ssk, const float* __restrict__ temp)
{
  int bh = blockIdx.x;
  int b = bh >> 3, h = bh & 7;
  int c = threadIdx.x;
  if (c >= 32) return;
  float* row = S + ((size_t)bh << 10) + c * 32;
  float invq = 1.f / fmaxf(sqrtf(ssq[b * 256 + h * 32 + c]), 1e-12f);
  float T = temp[h];
  float lg[32];
  float mx = -1e30f;
  for (int d = 0; d < 32; ++d) {
    float invk = 1.f / fmaxf(sqrtf(ssk[b * 256 + h * 32 + d]), 1e-12f);
    float v = row[d] * invq * invk * T;
    lg[d] = v;
    mx = fmaxf(mx, v);
  }
  float sum = 0.f;
  for (int d = 0; d < 32; ++d) { float e = expf(lg[d] - mx); lg[d] = e; sum += e; }
  float inv = 1.f / sum;
  for (int d = 0; d < 32; ++d) row[d] = lg[d] * inv;
}

// ---------------------------------------------------------------------------
// M[b][o][h*32+d] = sum_c w_proj[o][h*32+c] * attn[b,h,c,d]
__global__ __launch_bounds__(256) void mbuild_kernel(
    const float* __restrict__ attn, const float* __restrict__ wproj,
    float* __restrict__ M)
{
  int o = blockIdx.x, b = blockIdx.y;
  int col = threadIdx.x;
  int h = col >> 5, d = col & 31;
  const float* a = attn + (((size_t)b * 8 + h) << 10);
  const float* wp = wproj + o * 256 + h * 32;
  float s = 0.f;
  #pragma unroll
  for (int cc = 0; cc < 32; ++cc) s += wp[cc] * a[cc * 32 + d];
  M[((size_t)b * 256 + o) * 256 + col] = s;
}

// ---------------------------------------------------------------------------
extern "C" void kernel_launch(void* const* d_in, const int* in_sizes, int n_in,
                              void* d_out, int out_size, void* d_ws, size_t ws_size,
                              hipStream_t stream)
{
  const float* x      = (const float*)d_in[0];
  const float* k_v    = (const float*)d_in[1];
  const float* temp   = (const float*)d_in[2];
  const float* w_kR   = (const float*)d_in[3];
  const float* w_kI   = (const float*)d_in[4];
  const float* w_qR   = (const float*)d_in[5];
  const float* w_qdw  = (const float*)d_in[6];
  const float* w_kvI  = (const float*)d_in[7];
  const float* w_kvdw = (const float*)d_in[8];
  const float* w_proj = (const float*)d_in[9];
  float* out = (float*)d_out;

  float* ws   = (float*)d_ws;
  float* bufA = ws;                 // 64 MB
  float* bufB = ws + 16777216;      // 64 MB
  float* bufC = ws + 33554432;      // 64 MB
  float* sm   = ws + 50331648;      // small region at 192 MB
  float* mod  = sm;                 // 1024
  float* ssq  = sm + 1024;          // 1024 (q norms^2, plain store)
  float* ssk  = sm + 2048;          // 1024 (k norms^2, plain store)
  float* S    = sm + 3072;          // 32768 (Gram -> attn in place)
  float* M    = sm + 3072 + 32768;  // 262144 (fused attn+proj matrix)

  hipMemsetAsync(S, 0, (size_t)32768 * sizeof(float), stream);

  mod_kernel<<<dim3(4), dim3(256), 0, stream>>>(k_v, w_kR, w_kI, mod);

  // k_pre -> bufA ; kdw -> bufB (+ k norms)
  mgemm<<<dim3(128, 2, 4), dim3(256), 0, stream>>>(
      w_kvI, 64, 0, x, 192, 4194304, mod, bufA, 4194304, 64);
  dwconv_kernel<<<dim3(256, 4), dim3(256), 0, stream>>>(
      bufA, 4194304, w_kvdw, bufB, 4194304, ssk);

  // q_pre -> bufA ; qdw -> bufC (+ q norms)
  mgemm<<<dim3(128, 2, 4), dim3(256), 0, stream>>>(
      w_qR, 192, 0, x, 0, 4194304, mod, bufA, 4194304, 192);
  dwconv_kernel<<<dim3(256, 4), dim3(256), 0, stream>>>(
      bufA, 4194304, w_qdw, bufC, 4194304, ssq);

  // Gram: S = qdw . kdw^T over pixels (MFMA split-K)
  gram_kernel<<<dim3(16, 8, 4), dim3(256), 0, stream>>>(bufC, bufB, S);

  // v_pre -> bufA
  mgemm<<<dim3(128, 2, 4), dim3(256), 0, stream>>>(
      w_kvI + 256 * 64, 64, 0, x, 192, 4194304, mod, bufA, 4194304, 64);

  // attn (in place on S), then M = w_proj @ blockdiag(attn)
  softmax_kernel<<<dim3(32), dim3(64), 0, stream>>>(S, ssq, ssk, temp);
  mbuild_kernel<<<dim3(256, 4), dim3(256), 0, stream>>>(S, w_proj, M);

  // vdw -> bufC
  dwconv_kernel<<<dim3(256, 4), dim3(256), 0, stream>>>(
      bufA, 4194304, w_kvdw + 256 * 9, bufC, 4194304, (float*)nullptr);

  // out = M[b] @ vdw[b]
  mgemm<<<dim3(128, 2, 4), dim3(256), 0, stream>>>(
      M, 256, 65536, bufC, 0, 4194304, (const float*)nullptr, out, 4194304, 256);
}

// Round 4
// 321.766 us; speedup vs baseline: 1.0481x; 1.0481x over previous
//
#include <hip/hip_runtime.h>
#include <math.h>

#define HW 16384

typedef unsigned int uint;
typedef short bfrag __attribute__((ext_vector_type(8)));   // 8 bf16 (4 VGPRs)
typedef float f32x4 __attribute__((ext_vector_type(4)));   // 4 fp32 acc

union FragCvt { uint4 u; bfrag v; };

// round-to-nearest-even f32 -> bf16, pack two into a dword
__device__ inline uint pack2bf(float a, float b) {
  uint ua = __builtin_bit_cast(uint, a);
  uint ub = __builtin_bit_cast(uint, b);
  ua = (ua + 0x7FFFu + ((ua >> 16) & 1u)) >> 16;
  ub = (ub + 0x7FFFu + ((ub >> 16) & 1u)) & 0xFFFF0000u;
  return ua | ub;
}

// split 8 f32 into hi-bf16 frag and lo-bf16 frag (hi = RNE(x), lo = RNE(x-hi))
__device__ inline void cvt_hilo(float4 a, float4 b, bfrag& hi, bfrag& lo) {
  float v0[8] = {a.x, a.y, a.z, a.w, b.x, b.y, b.z, b.w};
  uint hv[4], lv[4];
  #pragma unroll
  for (int i = 0; i < 4; ++i) {
    float x0 = v0[2 * i], x1 = v0[2 * i + 1];
    uint h = pack2bf(x0, x1);
    float h0 = __builtin_bit_cast(float, h << 16);
    float h1 = __builtin_bit_cast(float, h & 0xFFFF0000u);
    hv[i] = h;
    lv[i] = pack2bf(x0 - h0, x1 - h1);
  }
  FragCvt ch, cl;
  ch.u = make_uint4(hv[0], hv[1], hv[2], hv[3]);
  cl.u = make_uint4(lv[0], lv[1], lv[2], lv[3]);
  hi = ch.v;
  lo = cl.v;
}

// ---------------------------------------------------------------------------
// mod[b,c] = 1 + (k_v[:, :192] @ w_kR.T) for c<192, else 1 + (k_v[:,192:] @ w_kI.T)
__global__ __launch_bounds__(256) void mod_kernel(
    const float* __restrict__ kv, const float* __restrict__ wkR,
    const float* __restrict__ wkI, float* __restrict__ mod)
{
  int b = blockIdx.x;
  int c = threadIdx.x;
  const float* kvb = kv + b * 256;
  float s = 0.f;
  if (c < 192) {
    const float* wr = wkR + c * 192;
    for (int j = 0; j < 192; ++j) s += kvb[j] * wr[j];
  } else {
    const float* wi = wkI + (c - 192) * 64;
    for (int j = 0; j < 64; ++j) s += kvb[192 + j] * wi[j];
  }
  mod[b * 256 + c] = 1.f + s;
}

// ---------------------------------------------------------------------------
// bf16-MFMA GEMM body: Y[128 x 128px tile] = W[128,K] @ (X[k,:] * mod[k])
// 256 threads = 4 waves (2x2 of 64x64), 4x4 frags of 16x16x32; f32 accum.
// Pipeline: X loads (HBM) for step i+1 issued before step i's MFMA block so
// their latency hides under frag-reads+MFMA and drains at next __syncthreads.
// W loads (L2-hot) issued at stage time. mod staged once into LDS (Ml),
// read as wave-uniform broadcast during B-pack.
__device__ __forceinline__ void mgemm_body(
    const float* __restrict__ Wt, int ldW,
    const float* __restrict__ Xt,      // X + b*bstride + c0*HW + nt*128
    const float* __restrict__ modc,    // mod + b*256 + c0, or null
    float* __restrict__ Yt,            // Y + b*bstride + mt*128*HW + nt*128
    int K, int t, unsigned short* Al, unsigned short* Bl, float* Ml)
{
  int w = t >> 6, l = t & 63;
  int wm = (w >> 1) * 64, wn = (w & 1) * 64;   // wm: outch base, wn: pixel base
  int lm = l & 15, lk = (l >> 4) * 8;

  int am = t >> 1, ako = (t & 1) * 16;     // A staging: row, k-offset (16 f32)
  int bn = t & 127, bo = (t >> 7) * 8;     // B staging: pixel, k-octet base

  // mod -> LDS once (visible after the first __syncthreads in the loop)
  Ml[t] = (modc && t < K) ? modc[t] : 1.f;

  f32x4 acc[4][4];
  #pragma unroll
  for (int fi = 0; fi < 4; ++fi)
    #pragma unroll
    for (int fj = 0; fj < 4; ++fj) acc[fi][fj] = {0.f, 0.f, 0.f, 0.f};

  float xr[2][8];
  auto load_x = [&](int k0) {
    #pragma unroll
    for (int i = 0; i < 2; ++i) {
      int kb = k0 + bo + i * 16;
      #pragma unroll
      for (int r = 0; r < 8; ++r)
        xr[i][r] = Xt[(size_t)(kb + r) * HW + bn];
    }
  };

  load_x(0);   // prologue prefetch

  for (int k0 = 0; k0 < K; k0 += 32) {
    __syncthreads();   // prev iteration's LDS frag reads done; Ml visible

    // ---- stage A (W loads here: L2-hot, short latency)
    {
      const float* wsrc = Wt + (size_t)am * ldW + k0 + ako;
      float4 a0 = *(const float4*)(wsrc);
      float4 a1 = *(const float4*)(wsrc + 4);
      float4 a2 = *(const float4*)(wsrc + 8);
      float4 a3 = *(const float4*)(wsrc + 12);
      uint4 aw0, aw1;
      aw0.x = pack2bf(a0.x, a0.y); aw0.y = pack2bf(a0.z, a0.w);
      aw0.z = pack2bf(a1.x, a1.y); aw0.w = pack2bf(a1.z, a1.w);
      aw1.x = pack2bf(a2.x, a2.y); aw1.y = pack2bf(a2.z, a2.w);
      aw1.z = pack2bf(a3.x, a3.y); aw1.w = pack2bf(a3.z, a3.w);
      *(uint4*)&Al[am * 40 + ako] = aw0;
      *(uint4*)&Al[am * 40 + ako + 8] = aw1;
    }

    // ---- stage B (mod-scale from LDS broadcast + convert)
    #pragma unroll
    for (int i = 0; i < 2; ++i) {
      float4 m0 = *(const float4*)&Ml[k0 + bo + i * 16];
      float4 m1 = *(const float4*)&Ml[k0 + bo + i * 16 + 4];
      uint4 bw;
      bw.x = pack2bf(xr[i][0] * m0.x, xr[i][1] * m0.y);
      bw.y = pack2bf(xr[i][2] * m0.z, xr[i][3] * m0.w);
      bw.z = pack2bf(xr[i][4] * m1.x, xr[i][5] * m1.y);
      bw.w = pack2bf(xr[i][6] * m1.z, xr[i][7] * m1.w);
      *(uint4*)&Bl[bn * 40 + bo + i * 16] = bw;
    }

    __syncthreads();

    // ---- fragments
    bfrag af[4], bfr[4];
    #pragma unroll
    for (int fj = 0; fj < 4; ++fj) {
      FragCvt cv;
      cv.u = *(const uint4*)&Al[(wm + fj * 16 + lm) * 40 + lk];
      af[fj] = cv.v;
    }
    #pragma unroll
    for (int fi = 0; fi < 4; ++fi) {
      FragCvt cv;
      cv.u = *(const uint4*)&Bl[(wn + fi * 16 + lm) * 40 + lk];
      bfr[fi] = cv.v;
    }

    // ---- prefetch next X tile: in flight across the MFMA block below,
    // drained at next iteration's first __syncthreads.
    if (k0 + 32 < K) load_x(k0 + 32);

    // ---- MFMA (pixel frag as A-operand -> C rows are pixels)
    #pragma unroll
    for (int fi = 0; fi < 4; ++fi)
      #pragma unroll
      for (int fj = 0; fj < 4; ++fj)
        acc[fi][fj] = __builtin_amdgcn_mfma_f32_16x16x32_bf16(
            bfr[fi], af[fj], acc[fi][fj], 0, 0, 0);
  }

  // ---- store C: rows = pixels -> acc[fi][fj] is float4 of 4 consecutive px
  int ph = (l >> 4) * 4;
  #pragma unroll
  for (int fi = 0; fi < 4; ++fi)
    #pragma unroll
    for (int fj = 0; fj < 4; ++fj)
      *(f32x4*)&Yt[(size_t)(wm + fj * 16 + lm) * HW + wn + fi * 16 + ph] =
          acc[fi][fj];
}

__global__ __launch_bounds__(256, 4) void mgemm(
    const float* __restrict__ W, int ldW, size_t Wbstride,
    const float* __restrict__ X, int c0, size_t Xbstride,
    const float* __restrict__ mod,
    float* __restrict__ Y, size_t Ybstride, int K)
{
  __shared__ unsigned short Al[128 * 40];
  __shared__ unsigned short Bl[128 * 40];
  __shared__ float Ml[256];
  int b = blockIdx.z, mt = blockIdx.y, nt = blockIdx.x;
  mgemm_body(W + (size_t)b * Wbstride + (size_t)mt * 128 * ldW, ldW,
             X + (size_t)b * Xbstride + (size_t)c0 * HW + nt * 128,
             mod ? mod + b * 256 + c0 : (const float*)nullptr,
             Y + (size_t)b * Ybstride + (size_t)mt * 128 * HW + nt * 128,
             K, threadIdx.x, Al, Bl, Ml);
}

// merged q (mt 0-1, K=192, c0=0) + k (mt 2-3, K=64, c0=192) projections
__global__ __launch_bounds__(256, 4) void mgemm_qk(
    const float* __restrict__ wqR, const float* __restrict__ wkvI,
    const float* __restrict__ X, const float* __restrict__ mod,
    float* __restrict__ Yq, float* __restrict__ Yk)
{
  __shared__ unsigned short Al[128 * 40];
  __shared__ unsigned short Bl[128 * 40];
  __shared__ float Ml[256];
  int b = blockIdx.z, mt = blockIdx.y, nt = blockIdx.x;
  if (mt < 2) {
    mgemm_body(wqR + (size_t)mt * 128 * 192, 192,
               X + (size_t)b * 4194304 + nt * 128,
               mod + b * 256,
               Yq + (size_t)b * 4194304 + (size_t)mt * 128 * HW + nt * 128,
               192, threadIdx.x, Al, Bl, Ml);
  } else {
    int m2 = mt - 2;
    mgemm_body(wkvI + (size_t)m2 * 128 * 64, 64,
               X + (size_t)b * 4194304 + (size_t)192 * HW + nt * 128,
               mod + b * 256 + 192,
               Yk + (size_t)b * 4194304 + (size_t)m2 * 128 * HW + nt * 128,
               64, threadIdx.x, Al, Bl, Ml);
  }
}

// ---------------------------------------------------------------------------
// depthwise 3x3, SAME zero pad. One block per (channel, batch).
__global__ __launch_bounds__(256) void dwconv_kernel(
    const float* __restrict__ in, size_t in_bstride,
    const float* __restrict__ wdw,
    float* __restrict__ out, size_t out_bstride,
    float* __restrict__ ssq)
{
  int c = blockIdx.x;
  int b = blockIdx.y;
  int t = threadIdx.x;
  int r = t >> 5;
  int xq = t & 31;

  const float4* ip4 = (const float4*)(in + (size_t)b * in_bstride + ((size_t)c << 14));
  float4* op4 = (float4*)(out + (size_t)b * out_bstride + ((size_t)c << 14));
  const float* wp = wdw + c * 9;
  float w0 = wp[0], w1 = wp[1], w2 = wp[2], w3 = wp[3], w4 = wp[4],
        w5 = wp[5], w6 = wp[6], w7 = wp[7], w8 = wp[8];

  const float4 z4 = make_float4(0.f, 0.f, 0.f, 0.f);
  int y0 = r << 4;

  float4 a = (y0 > 0) ? ip4[((y0 - 1) << 5) + xq] : z4;
  float4 bb = ip4[(y0 << 5) + xq];

  float aL = __shfl_up(a.w, 1);  if (xq == 0)  aL = 0.f;
  float aR = __shfl_down(a.x, 1); if (xq == 31) aR = 0.f;
  float bL = __shfl_up(bb.w, 1); if (xq == 0)  bL = 0.f;
  float bR = __shfl_down(bb.x, 1); if (xq == 31) bR = 0.f;

  float ss = 0.f;
  #pragma unroll
  for (int i = 0; i < 16; ++i) {
    int y = y0 + i;
    int yc = (y + 1 < 128) ? (y + 1) : 127;
    float4 cc = ip4[(yc << 5) + xq];
    if (y + 1 >= 128) { cc.x = 0.f; cc.y = 0.f; cc.z = 0.f; cc.w = 0.f; }
    float cL = __shfl_up(cc.w, 1);  if (xq == 0)  cL = 0.f;
    float cR = __shfl_down(cc.x, 1); if (xq == 31) cR = 0.f;

    float4 o;
    o.x = w0 * aL  + w1 * a.x + w2 * a.y +
          w3 * bL  + w4 * bb.x + w5 * bb.y +
          w6 * cL  + w7 * cc.x + w8 * cc.y;
    o.y = w0 * a.x + w1 * a.y + w2 * a.z +
          w3 * bb.x + w4 * bb.y + w5 * bb.z +
          w6 * cc.x + w7 * cc.y + w8 * cc.z;
    o.z = w0 * a.y + w1 * a.z + w2 * a.w +
          w3 * bb.y + w4 * bb.z + w5 * bb.w +
          w6 * cc.y + w7 * cc.z + w8 * cc.w;
    o.w = w0 * a.z + w1 * a.w + w2 * aR +
          w3 * bb.z + w4 * bb.w + w5 * bR +
          w6 * cc.z + w7 * cc.w + w8 * cR;

    op4[(y << 5) + xq] = o;
    ss += o.x * o.x + o.y * o.y + o.z * o.z + o.w * o.w;

    a = bb; aL = bL; aR = bR;
    bb = cc; bL = cL; bR = cR;
  }

  if (ssq) {
    #pragma unroll
    for (int off = 32; off > 0; off >>= 1) ss += __shfl_down(ss, off);
    __shared__ float red[4];
    if ((t & 63) == 0) red[t >> 6] = ss;
    __syncthreads();
    if (t == 0) ssq[b * 256 + c] = red[0] + red[1] + red[2] + red[3];
  }
}

// ---------------------------------------------------------------------------
// S[b,h,c,d] += sum_p qdw[b,h*32+c,p] * kdw[b,h*32+d,p]  (unnormalized Gram)
// MFMA split-K, hi/lo bf16 decomposition; no LDS staging in the main loop.
__global__ __launch_bounds__(256) void gram_kernel(
    const float* __restrict__ qdw, const float* __restrict__ kdw,
    float* __restrict__ S)
{
  int chunk = blockIdx.x, h = blockIdx.y, b = blockIdx.z;
  int t = threadIdx.x;
  int w = t >> 6, l = t & 63;
  int lm = l & 15;
  int lk8 = (l >> 4) * 8;

  const float* qh = qdw + (((size_t)b * 256 + h * 32) << 14);
  const float* kh = kdw + (((size_t)b * 256 + h * 32) << 14);
  const float* q0 = qh + ((size_t)lm << 14);
  const float* q1 = q0 + ((size_t)16 << 14);
  const float* k0 = kh + ((size_t)lm << 14);
  const float* k1 = k0 + ((size_t)16 << 14);

  int px0 = chunk * 1024 + w * 256 + lk8;

  f32x4 acc[2][2], accl[2][2];
  #pragma unroll
  for (int mi = 0; mi < 2; ++mi)
    #pragma unroll
    for (int nj = 0; nj < 2; ++nj) {
      acc[mi][nj] = {0.f, 0.f, 0.f, 0.f};
      accl[mi][nj] = {0.f, 0.f, 0.f, 0.f};
    }

  #pragma unroll 2
  for (int s = 0; s < 8; ++s) {
    int px = px0 + s * 32;
    float4 a0 = *(const float4*)(q0 + px);
    float4 a1 = *(const float4*)(q0 + px + 4);
    float4 a2 = *(const float4*)(q1 + px);
    float4 a3 = *(const float4*)(q1 + px + 4);
    float4 b0 = *(const float4*)(k0 + px);
    float4 b1 = *(const float4*)(k0 + px + 4);
    float4 b2 = *(const float4*)(k1 + px);
    float4 b3 = *(const float4*)(k1 + px + 4);

    bfrag qhF[2], qlF[2], khF[2], klF[2];
    cvt_hilo(a0, a1, qhF[0], qlF[0]);
    cvt_hilo(a2, a3, qhF[1], qlF[1]);
    cvt_hilo(b0, b1, khF[0], klF[0]);
    cvt_hilo(b2, b3, khF[1], klF[1]);

    #pragma unroll
    for (int mi = 0; mi < 2; ++mi)
      #pragma unroll
      for (int nj = 0; nj < 2; ++nj) {
        acc[mi][nj] = __builtin_amdgcn_mfma_f32_16x16x32_bf16(
            qhF[mi], khF[nj], acc[mi][nj], 0, 0, 0);
        accl[mi][nj] = __builtin_amdgcn_mfma_f32_16x16x32_bf16(
            qhF[mi], klF[nj], accl[mi][nj], 0, 0, 0);
        accl[mi][nj] = __builtin_amdgcn_mfma_f32_16x16x32_bf16(
            qlF[mi], khF[nj], accl[mi][nj], 0, 0, 0);
      }
  }

  // reduce the 4 waves' partial 32x32 tiles through LDS, then one
  // atomicAdd per element per block (16 adds/address across the grid).
  __shared__ float red[4][1024];
  int orow = (l >> 4) * 4;
  #pragma unroll
  for (int mi = 0; mi < 2; ++mi)
    #pragma unroll
    for (int nj = 0; nj < 2; ++nj)
      #pragma unroll
      for (int r = 0; r < 4; ++r)
        red[w][(mi * 16 + orow + r) * 32 + nj * 16 + lm] =
            acc[mi][nj][r] + accl[mi][nj][r];
  __syncthreads();
  float* Sp = S + (((size_t)b * 8 + h) << 10);
  for (int idx = t; idx < 1024; idx += 256)
    atomicAdd(&Sp[idx], red[0][idx] + red[1][idx] + red[2][idx] + red[3][idx]);
}

// ---------------------------------------------------------------------------
// in-place: S <- softmax_d( S / (max(|q|,eps)*max(|k|,eps)) * temp[h] )
__global__ __launch_bounds__(64) void softmax_kernel(
    float* __restrict__ S, const float* __restrict__ ssq,
    const float* __restrict__ ssk, const float* __restrict__ temp)
{
  int bh = blockIdx.x;
  int b = bh >> 3, h = bh & 7;
  int c = threadIdx.x;
  if (c >= 32) return;
  float* row = S + ((size_t)bh << 10) + c * 32;
  float invq = 1.f / fmaxf(sqrtf(ssq[b * 256 + h * 32 + c]), 1e-12f);
  float T = temp[h];
  float lg[32];
  float mx = -1e30f;
  for (int d = 0; d < 32; ++d) {
    float invk = 1.f / fmaxf(sqrtf(ssk[b * 256 + h * 32 + d]), 1e-12f);
    float v = row[d] * invq * invk * T;
    lg[d] = v;
    mx = fmaxf(mx, v);
  }
  float sum = 0.f;
  for (int d = 0; d < 32; ++d) { float e = expf(lg[d] - mx); lg[d] = e; sum += e; }
  float inv = 1.f / sum;
  for (int d = 0; d < 32; ++d) row[d] = lg[d] * inv;
}

// ---------------------------------------------------------------------------
// M[b][o][h*32+d] = sum_c w_proj[o][h*32+c] * attn[b,h,c,d]
__global__ __launch_bounds__(256) void mbuild_kernel(
    const float* __restrict__ attn, const float* __restrict__ wproj,
    float* __restrict__ M)
{
  int o = blockIdx.x, b = blockIdx.y;
  int col = threadIdx.x;
  int h = col >> 5, d = col & 31;
  const float* a = attn + (((size_t)b * 8 + h) << 10);
  const float* wp = wproj + o * 256 + h * 32;
  float s = 0.f;
  #pragma unroll
  for (int cc = 0; cc < 32; ++cc) s += wp[cc] * a[cc * 32 + d];
  M[((size_t)b * 256 + o) * 256 + col] = s;
}

// ---------------------------------------------------------------------------
extern "C" void kernel_launch(void* const* d_in, const int* in_sizes, int n_in,
                              void* d_out, int out_size, void* d_ws, size_t ws_size,
                              hipStream_t stream)
{
  const float* x      = (const float*)d_in[0];
  const float* k_v    = (const float*)d_in[1];
  const float* temp   = (const float*)d_in[2];
  const float* w_kR   = (const float*)d_in[3];
  const float* w_kI   = (const float*)d_in[4];
  const float* w_qR   = (const float*)d_in[5];
  const float* w_qdw  = (const float*)d_in[6];
  const float* w_kvI  = (const float*)d_in[7];
  const float* w_kvdw = (const float*)d_in[8];
  const float* w_proj = (const float*)d_in[9];
  float* out = (float*)d_out;

  float* ws   = (float*)d_ws;
  float* bufA = ws;                 // 64 MB
  float* bufB = ws + 16777216;      // 64 MB
  float* bufC = ws + 33554432;      // 64 MB
  float* sm   = ws + 50331648;      // small region at 192 MB
  float* mod  = sm;                 // 1024
  float* ssq  = sm + 1024;          // 1024 (q norms^2, plain store)
  float* ssk  = sm + 2048;          // 1024 (k norms^2, plain store)
  float* S    = sm + 3072;          // 32768 (Gram -> attn in place)
  float* M    = sm + 3072 + 32768;  // 262144 (fused attn+proj matrix)

  hipMemsetAsync(S, 0, (size_t)32768 * sizeof(float), stream);

  mod_kernel<<<dim3(4), dim3(256), 0, stream>>>(k_v, w_kR, w_kI, mod);

  // q_pre -> bufA ; k_pre -> bufB  (merged launch, 2048 blocks)
  mgemm_qk<<<dim3(128, 4, 4), dim3(256), 0, stream>>>(
      w_qR, w_kvI, x, mod, bufA, bufB);

  // kdw -> bufC (+ k norms)
  dwconv_kernel<<<dim3(256, 4), dim3(256), 0, stream>>>(
      bufB, 4194304, w_kvdw, bufC, 4194304, ssk);

  // qdw -> bufB (+ q norms; k_pre dead)
  dwconv_kernel<<<dim3(256, 4), dim3(256), 0, stream>>>(
      bufA, 4194304, w_qdw, bufB, 4194304, ssq);

  // Gram: S = qdw . kdw^T over pixels
  gram_kernel<<<dim3(16, 8, 4), dim3(256), 0, stream>>>(bufB, bufC, S);

  // v_pre -> bufA (q_pre dead)
  mgemm<<<dim3(128, 2, 4), dim3(256), 0, stream>>>(
      w_kvI + 256 * 64, 64, 0, x, 192, 4194304, mod, bufA, 4194304, 64);

  // attn (in place on S), then M = w_proj @ blockdiag(attn)
  softmax_kernel<<<dim3(32), dim3(64), 0, stream>>>(S, ssq, ssk, temp);
  mbuild_kernel<<<dim3(256, 4), dim3(256), 0, stream>>>(S, w_proj, M);

  // vdw -> bufC (kdw dead after gram)
  dwconv_kernel<<<dim3(256, 4), dim3(256), 0, stream>>>(
      bufA, 4194304, w_kvdw + 256 * 9, bufC, 4194304, (float*)nullptr);

  // out = M[b] @ vdw[b]
  mgemm<<<dim3(128, 2, 4), dim3(256), 0, stream>>>(
      M, 256, 65536, bufC, 0, 4194304, (const float*)nullptr, out, 4194304, 256);
}